// Round 3
// baseline (2274.301 us; speedup 1.0000x reference)
//
#include <hip/hip_runtime.h>
#include <hip/hip_bf16.h>

typedef short bf16x8 __attribute__((ext_vector_type(8)));
typedef float f32x4 __attribute__((ext_vector_type(4)));

// f32 -> bf16 round-to-nearest-even, as raw bits
__device__ __forceinline__ unsigned short f2b(float f) {
  union { float f; unsigned u; } v; v.f = f;
  unsigned r = v.u + 0x7FFF + ((v.u >> 16) & 1);
  return (unsigned short)(r >> 16);
}

// ---------------- zero-fill helpers (no hipMemsetAsync in capture) ----------
__global__ void zero_f32_kernel(float* __restrict__ p, long n) {
  long i = (long)blockIdx.x * blockDim.x + threadIdx.x;
  long stride = (long)gridDim.x * blockDim.x;
  for (; i < n; i += stride) p[i] = 0.f;
}
__global__ void zero_i32_kernel(int* __restrict__ p, int n) {
  int i = blockIdx.x * blockDim.x + threadIdx.x;
  if (i < n) p[i] = 0;
}

// ---------------- Router: logits -> top2 -> dispatch slots + shared gate ----
__global__ __launch_bounds__(64) void router_kernel(
    const float* __restrict__ h,       // chunk base [Tc, D]
    const float* __restrict__ gate_w,  // [D, 8]
    const float* __restrict__ wsg,     // [D]
    int* __restrict__ cnt, int* __restrict__ slot_e, int* __restrict__ slot_pos,
    float* __restrict__ slot_w, float* __restrict__ gout, int D) {
  int t = blockIdx.x;  // chunk-local token
  int lane = threadIdx.x;
  float acc[8] = {0.f, 0.f, 0.f, 0.f, 0.f, 0.f, 0.f, 0.f};
  float aw = 0.f;
  const float* hrow = h + (size_t)t * D;
  for (int d = lane; d < D; d += 64) {
    float hv = hrow[d];
    float4 g0 = *(const float4*)(gate_w + (size_t)d * 8);      // 32B aligned
    float4 g1 = *(const float4*)(gate_w + (size_t)d * 8 + 4);
    acc[0] += hv * g0.x; acc[1] += hv * g0.y; acc[2] += hv * g0.z; acc[3] += hv * g0.w;
    acc[4] += hv * g1.x; acc[5] += hv * g1.y; acc[6] += hv * g1.z; acc[7] += hv * g1.w;
    aw += hv * wsg[d];
  }
#pragma unroll
  for (int off = 32; off > 0; off >>= 1) {
#pragma unroll
    for (int e = 0; e < 8; ++e) acc[e] += __shfl_down(acc[e], off);
    aw += __shfl_down(aw, off);
  }
  if (lane == 0) {
    // top-2 on logits == top-2 on softmax probs; lax.top_k tie-break = lowest idx
    int e0 = 0; float m0v = acc[0];
#pragma unroll
    for (int e = 1; e < 8; ++e) if (acc[e] > m0v) { m0v = acc[e]; e0 = e; }
    int e1 = -1; float m1v = -3.4e38f;
#pragma unroll
    for (int e = 0; e < 8; ++e) if (e != e0 && acc[e] > m1v) { m1v = acc[e]; e1 = e; }
    if (e1 < 0) e1 = (e0 + 1) & 7;     // defensive (NaN logits)
    float r = __expf(m1v - m0v);       // p1/p0 <= 1; softmax denom cancels
    float w0 = 1.f / (1.f + r);
    float w1 = 1.f - w0;
    int p;
    p = atomicAdd(&cnt[e0], 1);
    slot_e[2 * t] = e0; slot_pos[2 * t] = p; slot_w[2 * t] = w0;
    p = atomicAdd(&cnt[e1], 1);
    slot_e[2 * t + 1] = e1; slot_pos[2 * t + 1] = p; slot_w[2 * t + 1] = w1;
    gout[t] = 1.f / (1.f + __expf(-aw));
  }
}

__global__ void scan_kernel(const int* __restrict__ cnt, int* __restrict__ offs, int E) {
  if (threadIdx.x == 0 && blockIdx.x == 0) {
    int s = 0;
    for (int e = 0; e < E; ++e) { offs[e] = s; s += cnt[e]; }
    offs[E] = s;
  }
}

__global__ void fill_kernel(const int* __restrict__ slot_e, const int* __restrict__ slot_pos,
                            const float* __restrict__ slot_w, const int* __restrict__ offs,
                            int* __restrict__ rowtok, float* __restrict__ roww, int n2T, int E) {
  int i = blockIdx.x * blockDim.x + threadIdx.x;
  if (i < n2T) {
    int e = slot_e[i];
    if (e < 0) e = 0; if (e >= E) e = E - 1;          // defensive
    int row = offs[e] + slot_pos[i];
    if (row < 0) row = 0; if (row >= n2T) row = n2T - 1;  // defensive
    rowtok[row] = i >> 1;   // chunk-local token index
    roww[row] = slot_w[i];
  }
}

// ---------------- Fused gate/up GEMM + silu*mul epilogue --------------------
// X: f32 [.,K]; B weights f32 [K,N]; converts to bf16 during LDS staging.
// 64x64 tile, BK=64, 4 waves each computing a 32x32 quadrant via 2x2 MFMA frags.
template <bool EXPERT>
__global__ __launch_bounds__(256) void gemm_act_kernel(
    const float* __restrict__ X,               // [maxTok, K] (chunk base)
    const float* __restrict__ BgAll,           // [(E)][K][N]
    const float* __restrict__ BuAll,           // [(E)][K][N]
    unsigned short* __restrict__ actOut,       // bf16 [., N]
    const int* __restrict__ offs, const int* __restrict__ rowtok,
    int K, int N, int rowsDirect, int maxTok) {
  int e = EXPERT ? blockIdx.z : 0;
  int base = 0, cnt = rowsDirect;
  if (EXPERT) { base = offs[e]; cnt = offs[e + 1] - base; }
  int m0 = blockIdx.y * 64;
  if (m0 >= cnt) return;
  int n0 = blockIdx.x * 64;

  const float* Bg = BgAll + (size_t)e * K * N;
  const float* Bu = BuAll + (size_t)e * K * N;

  __shared__ __align__(16) short As[64][72];   // 144B rows: 16B-aligned frag reads
  __shared__ __align__(16) short Bgs[64][72];  // stored transposed: [n][k]
  __shared__ __align__(16) short Bus[64][72];

  int tid = threadIdx.x;
  int lane = tid & 63, wave = tid >> 6;
  int quad = lane >> 4, l16 = lane & 15;
  int mBase = (wave >> 1) * 32, nBase = (wave & 1) * 32;

  f32x4 accG[2][2] = {};
  f32x4 accU[2][2] = {};

  int sr = tid >> 3;          // 0..31 staging row
  int sc = (tid & 7) * 8;     // staging col group (8 elems)

  size_t aRowOff[2];
#pragma unroll
  for (int rr = 0; rr < 2; ++rr) {
    int gr = m0 + sr + rr * 32;
    if (gr >= cnt) gr = cnt - 1;                       // clamp; masked at store
    int tokenRow = EXPERT ? rowtok[base + gr] : gr;
    if (tokenRow < 0) tokenRow = 0;                    // defensive
    if (tokenRow >= maxTok) tokenRow = maxTok - 1;
    aRowOff[rr] = (size_t)tokenRow * K;
  }

  for (int kt = 0; kt < K; kt += 64) {
#pragma unroll
    for (int rr = 0; rr < 2; ++rr) {
      int r = sr + rr * 32;
      const float* src = X + aRowOff[rr] + kt + sc;
      float4 v0 = *(const float4*)src;
      float4 v1 = *(const float4*)(src + 4);
      bf16x8 w;
      w[0] = (short)f2b(v0.x); w[1] = (short)f2b(v0.y); w[2] = (short)f2b(v0.z); w[3] = (short)f2b(v0.w);
      w[4] = (short)f2b(v1.x); w[5] = (short)f2b(v1.y); w[6] = (short)f2b(v1.z); w[7] = (short)f2b(v1.w);
      *(bf16x8*)&As[r][sc] = w;
    }
#pragma unroll
    for (int rr = 0; rr < 2; ++rr) {
      int kk = sr + rr * 32;
      const float* bg = Bg + (size_t)(kt + kk) * N + n0 + sc;
      const float* bu = Bu + (size_t)(kt + kk) * N + n0 + sc;
      float4 g0 = *(const float4*)bg; float4 g1 = *(const float4*)(bg + 4);
      float4 u0 = *(const float4*)bu; float4 u1 = *(const float4*)(bu + 4);
      Bgs[sc + 0][kk] = (short)f2b(g0.x); Bgs[sc + 1][kk] = (short)f2b(g0.y);
      Bgs[sc + 2][kk] = (short)f2b(g0.z); Bgs[sc + 3][kk] = (short)f2b(g0.w);
      Bgs[sc + 4][kk] = (short)f2b(g1.x); Bgs[sc + 5][kk] = (short)f2b(g1.y);
      Bgs[sc + 6][kk] = (short)f2b(g1.z); Bgs[sc + 7][kk] = (short)f2b(g1.w);
      Bus[sc + 0][kk] = (short)f2b(u0.x); Bus[sc + 1][kk] = (short)f2b(u0.y);
      Bus[sc + 2][kk] = (short)f2b(u0.z); Bus[sc + 3][kk] = (short)f2b(u0.w);
      Bus[sc + 4][kk] = (short)f2b(u1.x); Bus[sc + 5][kk] = (short)f2b(u1.y);
      Bus[sc + 6][kk] = (short)f2b(u1.z); Bus[sc + 7][kk] = (short)f2b(u1.w);
    }
    __syncthreads();
#pragma unroll
    for (int ks = 0; ks < 2; ++ks) {
      bf16x8 a[2], bg[2], bu[2];
#pragma unroll
      for (int i = 0; i < 2; ++i)
        a[i] = *(const bf16x8*)&As[mBase + i * 16 + l16][ks * 32 + quad * 8];
#pragma unroll
      for (int i = 0; i < 2; ++i) {
        bg[i] = *(const bf16x8*)&Bgs[nBase + i * 16 + l16][ks * 32 + quad * 8];
        bu[i] = *(const bf16x8*)&Bus[nBase + i * 16 + l16][ks * 32 + quad * 8];
      }
#pragma unroll
      for (int i = 0; i < 2; ++i)
#pragma unroll
        for (int j = 0; j < 2; ++j) {
          accG[i][j] = __builtin_amdgcn_mfma_f32_16x16x32_bf16(a[i], bg[j], accG[i][j], 0, 0, 0);
          accU[i][j] = __builtin_amdgcn_mfma_f32_16x16x32_bf16(a[i], bu[j], accU[i][j], 0, 0, 0);
        }
    }
    __syncthreads();
  }

#pragma unroll
  for (int i = 0; i < 2; ++i)
#pragma unroll
    for (int j = 0; j < 2; ++j)
#pragma unroll
      for (int r = 0; r < 4; ++r) {
        int row = mBase + i * 16 + quad * 4 + r;   // C/D: row = quad*4+reg
        int grow = m0 + row;
        if (grow < cnt) {
          int col = n0 + nBase + j * 16 + l16;     // C/D: col = lane&15
          float gv = accG[i][j][r], uv = accU[i][j][r];
          float sv = gv / (1.f + __expf(-gv)) * uv;
          actOut[(size_t)(base + grow) * N + col] = f2b(sv);
        }
      }
}

// ---------------- Down-proj GEMM; MODE 0: weighted atomic accum, 1: final ---
template <int MODE>
__global__ __launch_bounds__(256) void gemm_comb_kernel(
    const unsigned short* __restrict__ A,      // bf16 [., K] contiguous rows
    const float* __restrict__ BAll,            // f32 [(E)][K][N]
    const int* __restrict__ offs, const int* __restrict__ rowtok,
    const float* __restrict__ roww, float* __restrict__ accum,
    const float* __restrict__ gsig, float* __restrict__ out,
    int K, int N, int rowsDirect, int maxTok) {
  int e = (MODE == 0) ? blockIdx.z : 0;
  int base = 0, cnt = rowsDirect;
  if (MODE == 0) { base = offs[e]; cnt = offs[e + 1] - base; }
  int m0 = blockIdx.y * 64;
  if (m0 >= cnt) return;
  int n0 = blockIdx.x * 64;

  const float* B = BAll + (size_t)e * K * N;

  __shared__ __align__(16) short As[64][72];
  __shared__ __align__(16) short Bs[64][72];   // transposed [n][k]

  int tid = threadIdx.x;
  int lane = tid & 63, wave = tid >> 6;
  int quad = lane >> 4, l16 = lane & 15;
  int mBase = (wave >> 1) * 32, nBase = (wave & 1) * 32;

  f32x4 acc[2][2] = {};

  int sr = tid >> 3;
  int sc = (tid & 7) * 8;

  size_t aRowOff[2];
#pragma unroll
  for (int rr = 0; rr < 2; ++rr) {
    int gr = m0 + sr + rr * 32;
    if (gr >= cnt) gr = cnt - 1;
    aRowOff[rr] = (size_t)(base + gr) * K;     // A rows are contiguous (act layout)
  }

  for (int kt = 0; kt < K; kt += 64) {
#pragma unroll
    for (int rr = 0; rr < 2; ++rr) {
      int r = sr + rr * 32;
      *(bf16x8*)&As[r][sc] = *(const bf16x8*)(A + aRowOff[rr] + kt + sc);  // bf16 copy
    }
#pragma unroll
    for (int rr = 0; rr < 2; ++rr) {
      int kk = sr + rr * 32;
      const float* bp = B + (size_t)(kt + kk) * N + n0 + sc;
      float4 b0 = *(const float4*)bp; float4 b1 = *(const float4*)(bp + 4);
      Bs[sc + 0][kk] = (short)f2b(b0.x); Bs[sc + 1][kk] = (short)f2b(b0.y);
      Bs[sc + 2][kk] = (short)f2b(b0.z); Bs[sc + 3][kk] = (short)f2b(b0.w);
      Bs[sc + 4][kk] = (short)f2b(b1.x); Bs[sc + 5][kk] = (short)f2b(b1.y);
      Bs[sc + 6][kk] = (short)f2b(b1.z); Bs[sc + 7][kk] = (short)f2b(b1.w);
    }
    __syncthreads();
#pragma unroll
    for (int ks = 0; ks < 2; ++ks) {
      bf16x8 a[2], b[2];
#pragma unroll
      for (int i = 0; i < 2; ++i)
        a[i] = *(const bf16x8*)&As[mBase + i * 16 + l16][ks * 32 + quad * 8];
#pragma unroll
      for (int i = 0; i < 2; ++i)
        b[i] = *(const bf16x8*)&Bs[nBase + i * 16 + l16][ks * 32 + quad * 8];
#pragma unroll
      for (int i = 0; i < 2; ++i)
#pragma unroll
        for (int j = 0; j < 2; ++j)
          acc[i][j] = __builtin_amdgcn_mfma_f32_16x16x32_bf16(a[i], b[j], acc[i][j], 0, 0, 0);
    }
    __syncthreads();
  }

#pragma unroll
  for (int i = 0; i < 2; ++i)
#pragma unroll
    for (int j = 0; j < 2; ++j)
#pragma unroll
      for (int r = 0; r < 4; ++r) {
        int row = mBase + i * 16 + quad * 4 + r;
        int grow = m0 + row;
        if (grow < cnt) {
          int col = n0 + nBase + j * 16 + l16;
          float v = acc[i][j][r];
          if (MODE == 0) {
            int tok = rowtok[base + grow];
            if (tok < 0) tok = 0;                      // defensive
            if (tok >= maxTok) tok = maxTok - 1;
            float w = roww[base + grow];
            atomicAdd(&accum[(size_t)tok * N + col], w * v);
          } else {
            float res = accum[(size_t)grow * N + col] + gsig[grow] * v;
            out[(size_t)grow * N + col] = res;
          }
        }
      }
}

// ---------------------------------------------------------------------------
extern "C" void kernel_launch(void* const* d_in, const int* in_sizes, int n_in,
                              void* d_out, int out_size, void* d_ws, size_t ws_size,
                              hipStream_t stream) {
  const float* h       = (const float*)d_in[0];
  const float* gate_w  = (const float*)d_in[1];
  const float* w_gate  = (const float*)d_in[2];
  const float* w_up    = (const float*)d_in[3];
  const float* w_down  = (const float*)d_in[4];
  const float* ws_gate = (const float*)d_in[5];
  const float* ws_up   = (const float*)d_in[6];
  const float* ws_down = (const float*)d_in[7];
  const float* wsg     = (const float*)d_in[8];
  float* out = (float*)d_out;

  const int D  = in_sizes[8];            // 2048
  const int T  = in_sizes[0] / D;        // 8192
  const int E  = in_sizes[1] / D;        // 8
  const int F  = in_sizes[2] / (E * D);  // 1024
  const int FS = in_sizes[5] / D;        // 2048
  (void)n_in; (void)out_size;

  // ---- adaptive token chunking so scratch fits ws_size ----
  // per-token bytes: accum D*4 + act(bf16) max(2F,FS)*2 + g 4 + 5 slot arrays*8
  int actPerTok = (2 * F > FS ? 2 * F : FS);
  size_t perTok = (size_t)D * 4 + (size_t)actPerTok * 2 + 4 + 40;
  size_t avail = ws_size > 4096 ? ws_size - 4096 : 0;
  long TcL = (long)(avail / (perTok + 8));
  int Tc = (int)(TcL > T ? T : TcL);
  Tc &= ~63;
  if (Tc < 64) Tc = 64;  // below this nothing fits; assume ws_size >= ~1MB

  for (int t0 = 0; t0 < T; t0 += Tc) {
    int Tcur = (T - t0 < Tc) ? (T - t0) : Tc;
    const float* hC = h + (size_t)t0 * D;
    float* outC = out + (size_t)t0 * D;

    char* ws = (char*)d_ws;
    size_t off = 0;
    auto alloc = [&](size_t bytes) -> void* {
      void* p = ws + off;
      off += (bytes + 255) & ~(size_t)255;
      return p;
    };
    float* accum = (float*)alloc((size_t)Tc * D * sizeof(float));
    unsigned short* act = (unsigned short*)alloc((size_t)Tc * actPerTok * 2);
    float* g      = (float*)alloc((size_t)Tc * 4);
    int* cnt      = (int*)alloc((size_t)E * 4);
    int* offs     = (int*)alloc((size_t)(E + 1) * 4);
    int* slot_e   = (int*)alloc((size_t)2 * Tc * 4);
    int* slot_pos = (int*)alloc((size_t)2 * Tc * 4);
    float* slot_w = (float*)alloc((size_t)2 * Tc * 4);
    int* rowtok   = (int*)alloc((size_t)2 * Tc * 4);
    float* roww   = (float*)alloc((size_t)2 * Tc * 4);

    int gy = (Tcur + 63) / 64;

    zero_i32_kernel<<<1, 64, 0, stream>>>(cnt, E);
    zero_f32_kernel<<<1024, 256, 0, stream>>>(accum, (long)Tcur * D);

    router_kernel<<<Tcur, 64, 0, stream>>>(hC, gate_w, wsg, cnt, slot_e, slot_pos, slot_w, g, D);
    scan_kernel<<<1, 64, 0, stream>>>(cnt, offs, E);
    fill_kernel<<<(2 * Tcur + 255) / 256, 256, 0, stream>>>(slot_e, slot_pos, slot_w, offs,
                                                            rowtok, roww, 2 * Tcur, E);
    // Expert gate/up + silu*mul -> act[2*Tcur, F] (bf16)
    gemm_act_kernel<true><<<dim3(F / 64, gy, E), 256, 0, stream>>>(
        hC, w_gate, w_up, act, offs, rowtok, D, F, 0, Tcur);
    // Expert down-proj, weighted atomic accumulate into fp32 accum[Tcur, D]
    gemm_comb_kernel<0><<<dim3(D / 64, gy, E), 256, 0, stream>>>(
        act, w_down, offs, rowtok, roww, accum, nullptr, nullptr, F, D, 0, Tcur);
    // Shared expert gate/up -> act[Tcur, FS] (reuses act buffer)
    gemm_act_kernel<false><<<dim3(FS / 64, gy, 1), 256, 0, stream>>>(
        hC, ws_gate, ws_up, act, nullptr, nullptr, D, FS, Tcur, Tcur);
    // Shared down-proj + final combine: out = accum + sigmoid_gate * shared
    gemm_comb_kernel<1><<<dim3(D / 64, gy, 1), 256, 0, stream>>>(
        act, ws_down, nullptr, nullptr, nullptr, accum, g, outC, FS, D, Tcur, Tcur);
  }
}